// Round 5
// baseline (457.046 us; speedup 1.0000x reference)
//
#include <hip/hip_runtime.h>
#include <math.h>

typedef __bf16 bf16;
typedef bf16 bf16x8 __attribute__((ext_vector_type(8)));
typedef float f32x4 __attribute__((ext_vector_type(4)));

#define SENT 2048
#define LM 14          // Lanczos steps
#define BS_STRIDE 544  // B-tile nt-stride in elems (1088 B) -> staging writes 2-way max

// ---------------- k_pre: all transposes (fp32 -> bf16, k-contig) + CSR build, ONE launch ----
__global__ __launch_bounds__(256) void k_pre(
    const float* __restrict__ Wc, const float* __restrict__ Wq, const float* __restrict__ Wk,
    const float* __restrict__ Wv, const float* __restrict__ Wo, const float* __restrict__ W1,
    const float* __restrict__ W2, const float* __restrict__ x, const float* __restrict__ adj,
    bf16* __restrict__ WcT, bf16* __restrict__ WqT, bf16* __restrict__ WkT,
    bf16* __restrict__ WvT, bf16* __restrict__ WoT, bf16* __restrict__ W1T,
    bf16* __restrict__ W2T, bf16* __restrict__ xT,
    int* __restrict__ cnt, unsigned short* __restrict__ cols)
{
    __shared__ float tile[32][33];
    int z = blockIdx.z;
    if (z == 11) {  // CSR of adjacency (incl self loops), <=64/row, sentinel-padded
        int flat = blockIdx.y * 16 + blockIdx.x;
        if (flat >= 512) return;
        int row = flat * 4 + (threadIdx.x >> 6);
        int lane = threadIdx.x & 63;
        int base = 0;
        for (int c0 = 0; c0 < 2048; c0 += 64) {
            float a = adj[(long)row * 2048 + c0 + lane];
            unsigned long long m = __ballot(a != 0.0f);
            if (a != 0.0f) {
                int pos = base + __popcll(m & ((1ull << lane) - 1ull));
                if (pos < 64) cols[(long)row * 64 + pos] = (unsigned short)(c0 + lane);
            }
            base += __popcll(m);
        }
        int c = base < 64 ? base : 64;
        if (lane >= c) cols[(long)row * 64 + lane] = (unsigned short)SENT;
        if (lane == 0) cnt[row] = c;
        return;
    }
    const float* src; bf16* dst; int R, C;
    switch (z) {
        case 0: src = Wc; dst = WcT; R = 256; C = 256; break;
        case 1: src = Wq; dst = WqT; R = 256; C = 256; break;
        case 2: src = Wk; dst = WkT; R = 256; C = 256; break;
        case 3: src = Wv; dst = WvT; R = 256; C = 256; break;
        case 4: src = Wo; dst = WoT; R = 256; C = 256; break;
        case 5: src = W1; dst = W1T; R = 256; C = 512; break;
        case 6: src = W2; dst = W2T; R = 512; C = 256; break;
        default: {
            int b = z - 7;
            src = x + (long)b * 2048 * 256; dst = xT + (long)b * 256 * 2048;
            R = 2048; C = 256;
        }
    }
    int c0 = blockIdx.x * 32, r0 = blockIdx.y * 32;
    if (c0 >= C || r0 >= R) return;
    int tx = threadIdx.x & 31, ty = threadIdx.x >> 5;
#pragma unroll
    for (int j = 0; j < 4; ++j)
        tile[ty + 8 * j][tx] = src[(long)(r0 + ty + 8 * j) * C + c0 + tx];
    __syncthreads();
#pragma unroll
    for (int j = 0; j < 4; ++j)
        dst[(long)(c0 + ty + 8 * j) * R + r0 + tx] = (bf16)tile[tx][ty + 8 * j];
}

// ---------------- k_main: block 0 = Lanczos -> lam_max ; blocks 1..128 = xp0 = L@x --------
// GEMM: 256 thr, BM=64 BN=256 BK=32, frag-order LDS (conflict-free), double-buffered.
__global__ __launch_bounds__(256) void k_main(
    const int* __restrict__ cnt, const unsigned short* __restrict__ cols, float* __restrict__ lamOut,
    const float* __restrict__ L, const bf16* __restrict__ xT, bf16* __restrict__ xp0)
{
    __shared__ __align__(16) char lds[8192 + 34816];
    int t = threadIdx.x;
    int w = t >> 6, lane = t & 63;
    int q = lane >> 4, l15 = lane & 15;

    if (blockIdx.x != 0) {
        // ================= xp0 GEMM =================
        bf16* As0 = (bf16*)lds;            // ping-pong: +p*2048 elems (4096 B)
        bf16* Bs0 = (bf16*)(lds + 8192);   // ping-pong: +p*8704 elems (17408 B)
        int bx = blockIdx.x - 1;
        int rowBlk = (bx & 31) * 64;
        int z = bx >> 5;
        const bf16* BT = xT + (long)z * 256 * 2048;

        int ar = t >> 2, ag = t & 3;
        long aBase = (long)(rowBlk + ar) * 2048 + ag * 8;
        int aLds = (ar >> 4) * 512 + (ag * 16 + (ar & 15)) * 8;
        long bBase = (long)t * 2048;
        int bLds0 = (t >> 4) * BS_STRIDE + (t & 15) * 8;

        f32x4 acc[4][4];
#pragma unroll
        for (int i = 0; i < 4; ++i)
#pragma unroll
            for (int j = 0; j < 4; ++j) acc[i][j] = (f32x4){0.0f, 0.0f, 0.0f, 0.0f};

        uint4 ra; uint4 rb[4];
        auto loadT = [&](int kt) {
            const float* p = L + aBase + kt;
            float4 f0 = *(const float4*)p, f1 = *(const float4*)(p + 4);
            union { bf16 h[8]; uint4 u; } pk;
            pk.h[0]=(bf16)f0.x; pk.h[1]=(bf16)f0.y; pk.h[2]=(bf16)f0.z; pk.h[3]=(bf16)f0.w;
            pk.h[4]=(bf16)f1.x; pk.h[5]=(bf16)f1.y; pk.h[6]=(bf16)f1.z; pk.h[7]=(bf16)f1.w;
            ra = pk.u;
            const bf16* pb = BT + bBase + kt;
#pragma unroll
            for (int g = 0; g < 4; ++g) rb[g] = *(const uint4*)(pb + g * 8);
        };
        loadT(0);
        for (int it = 0; it < 64; ++it) {
            bf16* Asp = As0 + (it & 1) * 2048;
            bf16* Bsp = Bs0 + (it & 1) * 8704;
            *(uint4*)(Asp + aLds) = ra;
            bf16* bd = Bsp + bLds0;
#pragma unroll
            for (int g = 0; g < 4; ++g) *(uint4*)(bd + g * 128) = rb[g];
            __syncthreads();
            if (it + 1 < 64) loadT((it + 1) * 32);
            bf16x8 af[4], bfr[4];
#pragma unroll
            for (int mf = 0; mf < 4; ++mf) af[mf] = *(const bf16x8*)(Asp + mf * 512 + lane * 8);
#pragma unroll
            for (int i = 0; i < 4; ++i) bfr[i] = *(const bf16x8*)(Bsp + (w * 4 + i) * BS_STRIDE + lane * 8);
#pragma unroll
            for (int mf = 0; mf < 4; ++mf)
#pragma unroll
                for (int i = 0; i < 4; ++i)
                    acc[mf][i] = __builtin_amdgcn_mfma_f32_16x16x32_bf16(af[mf], bfr[i], acc[mf][i], 0, 0, 0);
        }
        long rowG = (long)z * 2048 + rowBlk + q * 4;
#pragma unroll
        for (int mf = 0; mf < 4; ++mf)
#pragma unroll
            for (int i = 0; i < 4; ++i) {
                int col = (w * 4 + i) * 16 + l15;
#pragma unroll
                for (int r = 0; r < 4; ++r)
                    xp0[(rowG + mf * 16 + r) * 256 + col] = (bf16)acc[mf][i][r];
            }
        return;
    }
    // ================= Lanczos (single block, 256 threads, 8 rows/thread) =================
    float* vcur = (float*)lds;                 // 2064
    float* vprev = vcur + 2064;                // 2064
    float* red  = vprev + 2064;                // 4
    float* bc   = red + 4;                     // 1
    float* alph = bc + 1;                      // LM
    float* betv = alph + LM;                   // LM

    auto bred = [&](float v) -> float {
#pragma unroll
        for (int off = 32; off >= 1; off >>= 1) v += __shfl_xor(v, off);
        if (lane == 0) red[w] = v;
        __syncthreads();
        if (t == 0) bc[0] = red[0] + red[1] + red[2] + red[3];
        __syncthreads();
        return bc[0];
    };

    int ci[8]; float cf[8]; int pr[8];
    int md = 0;
#pragma unroll
    for (int jj = 0; jj < 8; ++jj) {
        int i = t + 256 * jj;
        ci[jj] = cnt[i]; cf[jj] = (float)ci[jj];
        pr[jj] = (ci[jj] + 7) & ~7;
        md = max(md, ci[jj]);
    }
#pragma unroll
    for (int off = 32; off >= 1; off >>= 1) md = max(md, __shfl_xor(md, off));
    if (lane == 0) red[w] = (float)md;
    __syncthreads();
    if (t == 0) bc[0] = fmaxf(fmaxf(red[0], red[1]), fmaxf(red[2], red[3]));
    __syncthreads();
    float lamG = 2.0f * (bc[0] - 1.0f);
    float invG = lamG > 0.0f ? 1.0f / lamG : 0.0f;

    // init: vprev = 0, vcur = normalized pseudo-random
#pragma unroll
    for (int jj = 0; jj < 8; ++jj) {
        int i = t + 256 * jj;
        unsigned u = (unsigned)i * 2654435761u;
        u ^= u >> 16; u *= 2246822519u; u ^= u >> 13;
        float mag = 0.5f + (float)((u >> 9) & 1023) * (1.0f / 1024.0f);
        vcur[i] = (u & 1) ? mag : -mag;
        vprev[i] = 0.0f;
    }
    if (t == 0) { vcur[SENT] = 0.0f; vprev[SENT] = 0.0f; }
    __syncthreads();
    {
        float np = 0;
#pragma unroll
        for (int jj = 0; jj < 8; ++jj) { float v = vcur[t + 256 * jj]; np += v * v; }
        float ss = bred(np);
        float sc = rsqrtf(fmaxf(ss, 1e-30f));
#pragma unroll
        for (int jj = 0; jj < 8; ++jj) vcur[t + 256 * jj] *= sc;
        __syncthreads();
    }

    float bprev = 0.0f;
    for (int st = 0; st < LM; ++st) {
        float wv[8]; float ap = 0.0f;
#pragma unroll
        for (int jj = 0; jj < 8; ++jj) {
            int i = t + 256 * jj;
            const unsigned short* cl = cols + (long)i * 64;
            float sum = 0.0f;
            for (int j2 = 0; j2 < pr[jj]; j2 += 8) {
                uint4 qv = *(const uint4*)(cl + j2);
                sum += vcur[qv.x & 0xffff] + vcur[qv.x >> 16] + vcur[qv.y & 0xffff] + vcur[qv.y >> 16]
                     + vcur[qv.z & 0xffff] + vcur[qv.z >> 16] + vcur[qv.w & 0xffff] + vcur[qv.w >> 16];
            }
            float d = vcur[i];
            float y = (cf[jj] * d - sum) * invG - bprev * vprev[i];
            wv[jj] = y; ap += y * d;
        }
        float alpha = bred(ap);
        float np = 0.0f;
#pragma unroll
        for (int jj = 0; jj < 8; ++jj) {
            int i = t + 256 * jj;
            wv[jj] -= alpha * vcur[i];
            np += wv[jj] * wv[jj];
        }
        float ss = bred(np);
        float beta = sqrtf(ss);
        float binv = ss > 1e-20f ? 1.0f / beta : 0.0f;
#pragma unroll
        for (int jj = 0; jj < 8; ++jj) {
            int i = t + 256 * jj;
            float old = vcur[i];
            vprev[i] = old;
            vcur[i] = wv[jj] * binv;
        }
        if (t == 0) { alph[st] = alpha; betv[st] = beta; }
        bprev = beta;
        __syncthreads();
    }
    if (t == 0) {
        // Sturm bisection for lam_max of tridiagonal (alph, betv), scaled domain [0,1]
        float lo = 0.0f, hi = 1.00001f;
        for (int bi = 0; bi < 48; ++bi) {
            float mid = 0.5f * (lo + hi);
            int neg = 0;
            float d = alph[0] - mid;
            if (fabsf(d) < 1e-30f) d = -1e-30f;
            neg += (d < 0.0f);
            for (int i = 1; i < LM; ++i) {
                d = (alph[i] - mid) - betv[i - 1] * betv[i - 1] / d;
                if (fabsf(d) < 1e-30f) d = -1e-30f;
                neg += (d < 0.0f);
            }
            if (neg >= LM) hi = mid; else lo = mid;
        }
        lamOut[0] = lamG * 0.5f * (lo + hi) + 1e-8f;
    }
}

// ---------------- bf16 MFMA GEMM, 256 thr, BM=64 BN=256 BK=32, frag-order LDS, dbuf -------
// out[m][n] = sum_k A[m][k] * BT[n][k]
// TA: 1 = A bf16 | 2 = A_eff = (2/lam)*A_bf16 - Aaux_f32
// EPI: 0 = store bf16 | 1 = +bias,LN,relu,+resid -> f32+bf16 | 2 = +bias,+resid,LN -> f32(+bf16) | 3 = +bias,gelu -> bf16
template <int TA, int EPI>
__global__ __launch_bounds__(256) void k_gemm(
    const bf16* __restrict__ A0, const float* __restrict__ Aaux, const bf16* __restrict__ BTg,
    float* __restrict__ outF, bf16* __restrict__ outB,
    const float* __restrict__ bias, const float* __restrict__ resid,
    const float* __restrict__ gam, const float* __restrict__ bet,
    const float* __restrict__ lamPtr,
    int K, long aZ, long btZ, long outZrows, int ldOut)
{
    __shared__ __align__(16) char lds[8192 + 34816];
    bf16* As0 = (bf16*)lds;            // ping-pong: +p*2048 elems
    bf16* Bs0 = (bf16*)(lds + 8192);   // ping-pong: +p*8704 elems

    int t = threadIdx.x;
    int w = t >> 6, lane = t & 63;
    int q = lane >> 4, l15 = lane & 15;
    int rowBlk = blockIdx.x * 64;
    int colB = blockIdx.y * 256;
    const bf16* A = A0 + (long)blockIdx.z * aZ;
    const bf16* BT = BTg + (long)blockIdx.z * btZ + (long)blockIdx.y * 256 * (long)K;

    float s2 = 0.0f;
    if (TA == 2) s2 = 2.0f / lamPtr[0];

    int ar = t >> 2, ag = t & 3;
    long aBase = (long)(rowBlk + ar) * K + ag * 8;
    int aLds = (ar >> 4) * 512 + (ag * 16 + (ar & 15)) * 8;
    long bBase = (long)t * K;
    int bLds0 = (t >> 4) * BS_STRIDE + (t & 15) * 8;

    f32x4 acc[4][4];
#pragma unroll
    for (int i = 0; i < 4; ++i)
#pragma unroll
        for (int j = 0; j < 4; ++j) acc[i][j] = (f32x4){0.0f, 0.0f, 0.0f, 0.0f};

    uint4 ra; uint4 rb[4];
    auto loadT = [&](int kt) {
        if (TA == 1) {
            ra = *(const uint4*)(A + aBase + kt);
        } else {
            union { bf16 h[8]; uint4 u; } in; in.u = *(const uint4*)(A + aBase + kt);
            const float* p = Aaux + aBase + kt;
            float4 f0 = *(const float4*)p, f1 = *(const float4*)(p + 4);
            float xa[8] = {f0.x, f0.y, f0.z, f0.w, f1.x, f1.y, f1.z, f1.w};
            union { bf16 h[8]; uint4 u; } pk;
#pragma unroll
            for (int j = 0; j < 8; ++j) pk.h[j] = (bf16)(s2 * (float)in.h[j] - xa[j]);
            ra = pk.u;
        }
        const bf16* pb = BT + bBase + kt;
#pragma unroll
        for (int g = 0; g < 4; ++g) rb[g] = *(const uint4*)(pb + g * 8);
    };
    int nIter = K >> 5;
    loadT(0);
    for (int it = 0; it < nIter; ++it) {
        bf16* Asp = As0 + (it & 1) * 2048;
        bf16* Bsp = Bs0 + (it & 1) * 8704;
        *(uint4*)(Asp + aLds) = ra;
        bf16* bd = Bsp + bLds0;
#pragma unroll
        for (int g = 0; g < 4; ++g) *(uint4*)(bd + g * 128) = rb[g];
        __syncthreads();
        if (it + 1 < nIter) loadT((it + 1) * 32);
        bf16x8 af[4], bfr[4];
#pragma unroll
        for (int mf = 0; mf < 4; ++mf) af[mf] = *(const bf16x8*)(Asp + mf * 512 + lane * 8);
#pragma unroll
        for (int i = 0; i < 4; ++i) bfr[i] = *(const bf16x8*)(Bsp + (w * 4 + i) * BS_STRIDE + lane * 8);
#pragma unroll
        for (int mf = 0; mf < 4; ++mf)
#pragma unroll
            for (int i = 0; i < 4; ++i)
                acc[mf][i] = __builtin_amdgcn_mfma_f32_16x16x32_bf16(af[mf], bfr[i], acc[mf][i], 0, 0, 0);
    }

    long zBase = (long)blockIdx.z * outZrows;

    if (EPI == 0) {
#pragma unroll
        for (int mf = 0; mf < 4; ++mf)
#pragma unroll
            for (int i = 0; i < 4; ++i) {
                int col = colB + (w * 4 + i) * 16 + l15;
#pragma unroll
                for (int r = 0; r < 4; ++r)
                    outB[(zBase + rowBlk + mf * 16 + q * 4 + r) * (long)ldOut + col] = (bf16)acc[mf][i][r];
            }
        return;
    }
    if (EPI == 3) {
#pragma unroll
        for (int mf = 0; mf < 4; ++mf)
#pragma unroll
            for (int i = 0; i < 4; ++i) {
                int col = colB + (w * 4 + i) * 16 + l15;
                float bi = bias[col];
#pragma unroll
                for (int r = 0; r < 4; ++r) {
                    float v = acc[mf][i][r] + bi;
                    float g = 0.5f * v * (1.0f + erff(v * 0.70710678118654752440f));
                    outB[(zBase + rowBlk + mf * 16 + q * 4 + r) * (long)ldOut + col] = (bf16)g;
                }
            }
        return;
    }
    // EPI 1/2: layernorm across the 256-col row (cross-wave via LDS)
    float s[4][4], sq[4][4];
#pragma unroll
    for (int mf = 0; mf < 4; ++mf)
#pragma unroll
        for (int r = 0; r < 4; ++r) { s[mf][r] = 0.0f; sq[mf][r] = 0.0f; }
#pragma unroll
    for (int mf = 0; mf < 4; ++mf)
#pragma unroll
        for (int i = 0; i < 4; ++i) {
            int col = colB + (w * 4 + i) * 16 + l15;
            float bi = bias[col];
#pragma unroll
            for (int r = 0; r < 4; ++r) {
                float v = acc[mf][i][r] + bi;
                if (EPI == 2) v += resid[(zBase + rowBlk + mf * 16 + q * 4 + r) * 256 + col];
                acc[mf][i][r] = v;
                s[mf][r] += v; sq[mf][r] += v * v;
            }
        }
#pragma unroll
    for (int off = 1; off <= 8; off <<= 1)
#pragma unroll
        for (int mf = 0; mf < 4; ++mf)
#pragma unroll
            for (int r = 0; r < 4; ++r) {
                s[mf][r] += __shfl_xor(s[mf][r], off);
                sq[mf][r] += __shfl_xor(sq[mf][r], off);
            }
    __syncthreads();  // LDS buffers free; reuse for LN scratch
    float* sLN = (float*)lds;           // [4 waves][64 rows][2]
    float* mr  = (float*)(lds + 2048);  // [64 rows][2]
    if (l15 == 0) {
#pragma unroll
        for (int mf = 0; mf < 4; ++mf)
#pragma unroll
            for (int r = 0; r < 4; ++r) {
                int row = mf * 16 + q * 4 + r;
                sLN[(w * 64 + row) * 2 + 0] = s[mf][r];
                sLN[(w * 64 + row) * 2 + 1] = sq[mf][r];
            }
    }
    __syncthreads();
    if (t < 64) {
        float ss = 0, sqq = 0;
#pragma unroll
        for (int w4 = 0; w4 < 4; ++w4) {
            ss += sLN[(w4 * 64 + t) * 2 + 0];
            sqq += sLN[(w4 * 64 + t) * 2 + 1];
        }
        float mean = ss * (1.0f / 256.0f);
        float var = sqq * (1.0f / 256.0f) - mean * mean;
        mr[t * 2 + 0] = mean;
        mr[t * 2 + 1] = rsqrtf(var + 1e-5f);
    }
    __syncthreads();
#pragma unroll
    for (int mf = 0; mf < 4; ++mf)
#pragma unroll
        for (int r = 0; r < 4; ++r) {
            int row = mf * 16 + q * 4 + r;
            float mean = mr[row * 2 + 0], rs = mr[row * 2 + 1];
            long gRow = zBase + rowBlk + row;
#pragma unroll
            for (int i = 0; i < 4; ++i) {
                int col = colB + (w * 4 + i) * 16 + l15;
                float v = (acc[mf][i][r] - mean) * rs * gam[col] + bet[col];
                if (EPI == 1) v = fmaxf(v, 0.0f) + resid[gRow * 256 + col];
                long oi = gRow * (long)ldOut + col;
                outF[oi] = v;
                if (outB) outB[oi] = (bf16)v;
            }
        }
}

// ---------------- sparse gather attention: block=(b,row), wave=head, lane=dim ----------------
__global__ __launch_bounds__(256) void k_attn(const bf16* __restrict__ qg, const bf16* __restrict__ kg,
                                              const bf16* __restrict__ vg, bf16* __restrict__ og,
                                              const int* __restrict__ cnt, const unsigned short* __restrict__ cols)
{
    __shared__ unsigned short sc[64];
    __shared__ float sp[4][64];
    int row = blockIdx.x;
    int b = row >> 11, i = row & 2047;
    int tid = threadIdx.x, h = tid >> 6, lane = tid & 63;
    int c = cnt[i];
    if (tid < 64) sc[tid] = cols[(long)i * 64 + tid];
    __syncthreads();
    long qoff = (long)row * 256 + h * 64 + lane;
    float qd = (float)qg[qoff];
    long kvBase = (long)b * 2048;
    for (int j = 0; j < c; ++j) {
        int col = sc[j];
        float kd = (float)kg[(kvBase + col) * 256 + h * 64 + lane];
        float p = qd * kd;
#pragma unroll
        for (int off = 32; off >= 1; off >>= 1) p += __shfl_xor(p, off);
        if (lane == 0) sp[h][j] = p * 0.125f;
    }
    __syncthreads();
    float sj = (lane < c) ? sp[h][lane] : -3.0e38f;
    float mx = sj;
#pragma unroll
    for (int off = 32; off >= 1; off >>= 1) mx = fmaxf(mx, __shfl_xor(mx, off));
    float e = (lane < c) ? __expf(sj - mx) : 0.0f;
    float ssum = e;
#pragma unroll
    for (int off = 32; off >= 1; off >>= 1) ssum += __shfl_xor(ssum, off);
    if (lane < c) sp[h][lane] = e / ssum;
    __syncthreads();
    float acc = 0.0f;
    for (int j = 0; j < c; ++j) {
        int col = sc[j];
        acc += sp[h][j] * (float)vg[(kvBase + col) * 256 + h * 64 + lane];
    }
    og[qoff] = (bf16)acc;
}

// ---------------- launcher ----------------
extern "C" void kernel_launch(void* const* d_in, const int* in_sizes, int n_in,
                              void* d_out, int out_size, void* d_ws, size_t ws_size,
                              hipStream_t stream)
{
    const float* x   = (const float*)d_in[0];
    const float* L   = (const float*)d_in[1];
    const float* adj = (const float*)d_in[2];
    const float* Wc  = (const float*)d_in[3];
    const float* bc  = (const float*)d_in[4];
    const float* g1  = (const float*)d_in[5];
    const float* be1 = (const float*)d_in[6];
    const float* Wq  = (const float*)d_in[7];
    const float* Wk  = (const float*)d_in[8];
    const float* Wv  = (const float*)d_in[9];
    const float* Wo  = (const float*)d_in[10];
    const float* bo  = (const float*)d_in[11];
    const float* g2  = (const float*)d_in[12];
    const float* be2 = (const float*)d_in[13];
    const float* W1  = (const float*)d_in[14];
    const float* b1  = (const float*)d_in[15];
    const float* W2  = (const float*)d_in[16];
    const float* b2  = (const float*)d_in[17];
    const float* g3  = (const float*)d_in[18];
    const float* be3 = (const float*)d_in[19];
    float* out = (float*)d_out;

    char* ws = (char*)d_ws;
    size_t off = 0;
    auto alloc = [&](size_t bytes) -> void* {
        void* p = ws + off;
        off = (off + bytes + 255) & ~(size_t)255;
        return p;
    };
    float* lam           = (float*)alloc(256);
    int* cnt             = (int*)alloc(2048 * 4);
    unsigned short* cols = (unsigned short*)alloc(2048 * 64 * 2);
    bf16* WcT = (bf16*)alloc(65536 * 2);
    bf16* WqT = (bf16*)alloc(65536 * 2);   // WqT,WkT,WvT contiguous (btZ = 65536)
    bf16* WkT = (bf16*)alloc(65536 * 2);
    bf16* WvT = (bf16*)alloc(65536 * 2);
    bf16* WoT = (bf16*)alloc(65536 * 2);
    bf16* W1T = (bf16*)alloc(131072 * 2);
    bf16* W2T = (bf16*)alloc(131072 * 2);
    bf16* xT  = (bf16*)alloc((size_t)4 * 256 * 2048 * 2);
    bf16* xp0 = (bf16*)alloc((size_t)8192 * 256 * 2);
    float* x1f = (float*)alloc((size_t)8192 * 256 * 4);
    bf16* x1b  = (bf16*)alloc((size_t)8192 * 256 * 2);
    bf16* qb   = (bf16*)alloc((size_t)3 * 8192 * 256 * 2);
    bf16* ob   = (bf16*)alloc((size_t)8192 * 256 * 2);
    float* x2f = (float*)alloc((size_t)8192 * 256 * 4);
    bf16* x2b  = (bf16*)alloc((size_t)8192 * 256 * 2);
    bf16* m1   = (bf16*)alloc((size_t)8192 * 512 * 2);
    (void)in_sizes; (void)n_in; (void)out_size; (void)ws_size;

    dim3 blk(256);
    // transposes + CSR, one launch
    k_pre<<<dim3(16, 64, 12), blk, 0, stream>>>(Wc, Wq, Wk, Wv, Wo, W1, W2, x, adj,
                                                WcT, WqT, WkT, WvT, WoT, W1T, W2T, xT, cnt, cols);
    // block 0: Lanczos -> lam ; blocks 1..128: xp0[b] = L @ x[b]
    k_main<<<dim3(129), blk, 0, stream>>>(cnt, cols, lam, L, xT, xp0);
    // x1 = relu(LN((s2*xp0 - x)@Wc + bc; g1,be1)) + x
    k_gemm<2, 1><<<dim3(128, 1, 1), blk, 0, stream>>>(
        xp0, x, WcT, x1f, x1b, bc, x, g1, be1, lam,
        256, 0L, 0L, 0L, 256);
    // q,k,v = x1 @ {Wq,Wk,Wv}
    k_gemm<1, 0><<<dim3(128, 1, 3), blk, 0, stream>>>(
        x1b, nullptr, WqT, nullptr, qb, nullptr, nullptr, nullptr, nullptr, nullptr,
        256, 0L, 65536L, 8192L, 256);
    // sparse masked attention
    bf16* kb  = qb + (size_t)8192 * 256;
    bf16* vb2 = qb + (size_t)2 * 8192 * 256;
    k_attn<<<dim3(8192), blk, 0, stream>>>(qb, kb, vb2, ob, cnt, cols);
    // x2 = LN(x1 + o@Wo + bo; g2,be2)
    k_gemm<1, 2><<<dim3(128, 1, 1), blk, 0, stream>>>(
        ob, nullptr, WoT, x2f, x2b, bo, x1f, g2, be2, nullptr,
        256, 0L, 0L, 0L, 256);
    // m1 = gelu(x2@W1 + b1)
    k_gemm<1, 3><<<dim3(128, 2, 1), blk, 0, stream>>>(
        x2b, nullptr, W1T, nullptr, m1, b1, nullptr, nullptr, nullptr, nullptr,
        256, 0L, 0L, 0L, 512);
    // out = LN(x2 + m1@W2 + b2; g3,be3)
    k_gemm<1, 2><<<dim3(128, 1, 1), blk, 0, stream>>>(
        m1, nullptr, W2T, out, nullptr, b2, x2f, g3, be3, nullptr,
        512, 0L, 0L, 0L, 256);
}

// Round 6
// 414.644 us; speedup vs baseline: 1.1023x; 1.1023x over previous
//
#include <hip/hip_runtime.h>
#include <math.h>

typedef __bf16 bf16;
typedef bf16 bf16x8 __attribute__((ext_vector_type(8)));
typedef float f32x4 __attribute__((ext_vector_type(4)));

#define SENT 2048
#define LM 14          // Lanczos steps
#define BS_STRIDE 544  // B-tile frag stride in elems

// ---------------- k_pre: all transposes (fp32 -> bf16, k-contig) + CSR build, ONE launch ----
__global__ __launch_bounds__(256) void k_pre(
    const float* __restrict__ Wc, const float* __restrict__ Wq, const float* __restrict__ Wk,
    const float* __restrict__ Wv, const float* __restrict__ Wo, const float* __restrict__ W1,
    const float* __restrict__ W2, const float* __restrict__ x, const float* __restrict__ adj,
    bf16* __restrict__ WcT, bf16* __restrict__ WqT, bf16* __restrict__ WkT,
    bf16* __restrict__ WvT, bf16* __restrict__ WoT, bf16* __restrict__ W1T,
    bf16* __restrict__ W2T, bf16* __restrict__ xT,
    int* __restrict__ cnt, unsigned short* __restrict__ cols)
{
    __shared__ float tile[32][33];
    int z = blockIdx.z;
    if (z == 11) {  // CSR of adjacency (incl self loops), <=64/row, sentinel-padded
        int flat = blockIdx.y * 16 + blockIdx.x;
        if (flat >= 512) return;
        int row = flat * 4 + (threadIdx.x >> 6);
        int lane = threadIdx.x & 63;
        int base = 0;
        for (int c0 = 0; c0 < 2048; c0 += 64) {
            float a = adj[(long)row * 2048 + c0 + lane];
            unsigned long long m = __ballot(a != 0.0f);
            if (a != 0.0f) {
                int pos = base + __popcll(m & ((1ull << lane) - 1ull));
                if (pos < 64) cols[(long)row * 64 + pos] = (unsigned short)(c0 + lane);
            }
            base += __popcll(m);
        }
        int c = base < 64 ? base : 64;
        if (lane >= c) cols[(long)row * 64 + lane] = (unsigned short)SENT;
        if (lane == 0) cnt[row] = c;
        return;
    }
    const float* src; bf16* dst; int R, C;
    switch (z) {
        case 0: src = Wc; dst = WcT; R = 256; C = 256; break;
        case 1: src = Wq; dst = WqT; R = 256; C = 256; break;
        case 2: src = Wk; dst = WkT; R = 256; C = 256; break;
        case 3: src = Wv; dst = WvT; R = 256; C = 256; break;
        case 4: src = Wo; dst = WoT; R = 256; C = 256; break;
        case 5: src = W1; dst = W1T; R = 256; C = 512; break;
        case 6: src = W2; dst = W2T; R = 512; C = 256; break;
        default: {
            int b = z - 7;
            src = x + (long)b * 2048 * 256; dst = xT + (long)b * 256 * 2048;
            R = 2048; C = 256;
        }
    }
    int c0 = blockIdx.x * 32, r0 = blockIdx.y * 32;
    if (c0 >= C || r0 >= R) return;
    int tx = threadIdx.x & 31, ty = threadIdx.x >> 5;
#pragma unroll
    for (int j = 0; j < 4; ++j)
        tile[ty + 8 * j][tx] = src[(long)(r0 + ty + 8 * j) * C + c0 + tx];
    __syncthreads();
#pragma unroll
    for (int j = 0; j < 4; ++j)
        dst[(long)(c0 + ty + 8 * j) * R + r0 + tx] = (bf16)tile[tx][ty + 8 * j];
}

// =============== shared GEMM tile machinery: 512 thr, 8 waves, BM=64 BN=256 BK=32 ==========
// wave w: row-frags rh = (w&1)*2 + {0,1}; col-frags (w>>1)*4 + {0..3}. acc[2][4].
// A LDS frag-order [mf][lane][8] (512 elems/frag); B [nf][lane][8] stride BS_STRIDE.

// ---------------- k_main: block 0 = Lanczos -> lam_max ; blocks 1..128 = xp0 = L@x --------
__global__ __launch_bounds__(512) void k_main(
    const int* __restrict__ cnt, const unsigned short* __restrict__ cols, float* __restrict__ lamOut,
    const float* __restrict__ L, const bf16* __restrict__ xT, bf16* __restrict__ xp0)
{
    __shared__ __align__(16) char lds[8192 + 34816];
    int t = threadIdx.x;
    int w = t >> 6, lane = t & 63;
    int q = lane >> 4, l15 = lane & 15;

    if (blockIdx.x != 0) {
        // ================= xp0 GEMM =================
        bf16* As0 = (bf16*)lds;            // ping-pong +p*2048 elems
        bf16* Bs0 = (bf16*)(lds + 8192);   // ping-pong +p*8704 elems
        int bx = blockIdx.x - 1;
        int rowBlk = (bx & 31) * 64;
        int z = bx >> 5;
        const bf16* BT = xT + (long)z * 256 * 2048;

        int ar = t >> 2, ag = t & 3;                       // t<256: A stage, 8 elems
        long aBase = (long)(rowBlk + ar) * 2048 + ag * 8;
        int aLds = (ar >> 4) * 512 + (ag * 16 + (ar & 15)) * 8;
        int br = t >> 1, bg = t & 1;                       // all: B stage, 16 elems
        long bBase = (long)br * 2048 + bg * 16;
        int bLds = (br >> 4) * BS_STRIDE + (br & 15) * 8 + bg * 256;
        int wm = (w & 1) * 2, wn = (w >> 1) * 4;

        f32x4 acc[2][4];
#pragma unroll
        for (int i = 0; i < 2; ++i)
#pragma unroll
            for (int j = 0; j < 4; ++j) acc[i][j] = (f32x4){0.0f, 0.0f, 0.0f, 0.0f};

        uint4 ra; uint4 rb[2];
        auto loadT = [&](int kt) {
            if (t < 256) {
                const float* p = L + aBase + kt;
                float4 f0 = *(const float4*)p, f1 = *(const float4*)(p + 4);
                union { bf16 h[8]; uint4 u; } pk;
                pk.h[0]=(bf16)f0.x; pk.h[1]=(bf16)f0.y; pk.h[2]=(bf16)f0.z; pk.h[3]=(bf16)f0.w;
                pk.h[4]=(bf16)f1.x; pk.h[5]=(bf16)f1.y; pk.h[6]=(bf16)f1.z; pk.h[7]=(bf16)f1.w;
                ra = pk.u;
            }
            const bf16* pb = BT + bBase + kt;
            rb[0] = *(const uint4*)pb;
            rb[1] = *(const uint4*)(pb + 8);
        };
        loadT(0);
        for (int it = 0; it < 64; ++it) {
            bf16* Asp = As0 + (it & 1) * 2048;
            bf16* Bsp = Bs0 + (it & 1) * 8704;
            if (t < 256) *(uint4*)(Asp + aLds) = ra;
            *(uint4*)(Bsp + bLds) = rb[0];
            *(uint4*)(Bsp + bLds + 128) = rb[1];
            __syncthreads();
            if (it + 1 < 64) loadT((it + 1) * 32);
            bf16x8 af[2], bfr[4];
#pragma unroll
            for (int mf = 0; mf < 2; ++mf) af[mf] = *(const bf16x8*)(Asp + (wm + mf) * 512 + lane * 8);
#pragma unroll
            for (int i = 0; i < 4; ++i) bfr[i] = *(const bf16x8*)(Bsp + (wn + i) * BS_STRIDE + lane * 8);
#pragma unroll
            for (int mf = 0; mf < 2; ++mf)
#pragma unroll
                for (int i = 0; i < 4; ++i)
                    acc[mf][i] = __builtin_amdgcn_mfma_f32_16x16x32_bf16(af[mf], bfr[i], acc[mf][i], 0, 0, 0);
        }
        long rowG = (long)z * 2048 + rowBlk + q * 4;
#pragma unroll
        for (int mf = 0; mf < 2; ++mf)
#pragma unroll
            for (int i = 0; i < 4; ++i) {
                int col = (wn + i) * 16 + l15;
#pragma unroll
                for (int r = 0; r < 4; ++r)
                    xp0[(rowG + (wm + mf) * 16 + r) * 256 + col] = (bf16)acc[mf][i][r];
            }
        return;
    }
    // ================= Lanczos (single block, 512 threads, 4 rows/thread) =================
    float* vcur = (float*)lds;                 // 2064
    float* vprev = vcur + 2064;                // 2064
    float* red  = vprev + 2064;                // 8
    float* bc   = red + 8;                     // 1
    float* alph = bc + 1;                      // LM
    float* betv = alph + LM;                   // LM

    auto bred = [&](float v) -> float {
#pragma unroll
        for (int off = 32; off >= 1; off >>= 1) v += __shfl_xor(v, off);
        if (lane == 0) red[w] = v;
        __syncthreads();
        if (t == 0) {
            float s = 0;
            for (int i = 0; i < 8; ++i) s += red[i];
            bc[0] = s;
        }
        __syncthreads();
        return bc[0];
    };

    int ci[4]; float cf[4]; int pr[4];
    int md = 0;
#pragma unroll
    for (int jj = 0; jj < 4; ++jj) {
        int i = t + 512 * jj;
        ci[jj] = cnt[i]; cf[jj] = (float)ci[jj];
        pr[jj] = (ci[jj] + 7) & ~7;
        md = max(md, ci[jj]);
    }
#pragma unroll
    for (int off = 32; off >= 1; off >>= 1) md = max(md, __shfl_xor(md, off));
    if (lane == 0) red[w] = (float)md;
    __syncthreads();
    if (t == 0) {
        float m = 0;
        for (int i = 0; i < 8; ++i) m = fmaxf(m, red[i]);
        bc[0] = m;
    }
    __syncthreads();
    float lamG = 2.0f * (bc[0] - 1.0f);
    float invG = lamG > 0.0f ? 1.0f / lamG : 0.0f;

    // init: vprev = 0, vcur = pseudo-random +/- (avoid the 0-eigenvector 1)
#pragma unroll
    for (int jj = 0; jj < 4; ++jj) {
        int i = t + 512 * jj;
        unsigned u = (unsigned)i * 2654435761u;
        u ^= u >> 16; u *= 2246822519u; u ^= u >> 13;
        float mag = 0.5f + (float)((u >> 9) & 1023) * (1.0f / 1024.0f);
        vcur[i] = (u & 1) ? mag : -mag;
        vprev[i] = 0.0f;
    }
    if (t == 0) { vcur[SENT] = 0.0f; vprev[SENT] = 0.0f; }
    __syncthreads();
    {
        float np = 0;
#pragma unroll
        for (int jj = 0; jj < 4; ++jj) { float v = vcur[t + 512 * jj]; np += v * v; }
        float ss = bred(np);
        float sc = rsqrtf(fmaxf(ss, 1e-30f));
#pragma unroll
        for (int jj = 0; jj < 4; ++jj) vcur[t + 512 * jj] *= sc;
        __syncthreads();
    }

    float bprev = 0.0f;
    for (int st = 0; st < LM; ++st) {
        float wv[4]; float ap = 0.0f;
#pragma unroll
        for (int jj = 0; jj < 4; ++jj) {
            int i = t + 512 * jj;
            const unsigned short* cl = cols + (long)i * 64;
            float sum = 0.0f;
            for (int j2 = 0; j2 < pr[jj]; j2 += 8) {
                uint4 qv = *(const uint4*)(cl + j2);
                sum += vcur[qv.x & 0xffff] + vcur[qv.x >> 16] + vcur[qv.y & 0xffff] + vcur[qv.y >> 16]
                     + vcur[qv.z & 0xffff] + vcur[qv.z >> 16] + vcur[qv.w & 0xffff] + vcur[qv.w >> 16];
            }
            float d = vcur[i];
            float y = (cf[jj] * d - sum) * invG - bprev * vprev[i];
            wv[jj] = y; ap += y * d;
        }
        float alpha = bred(ap);
        float np = 0.0f;
#pragma unroll
        for (int jj = 0; jj < 4; ++jj) {
            int i = t + 512 * jj;
            wv[jj] -= alpha * vcur[i];
            np += wv[jj] * wv[jj];
        }
        float ss = bred(np);
        float beta = sqrtf(ss);
        float binv = ss > 1e-20f ? 1.0f / beta : 0.0f;
#pragma unroll
        for (int jj = 0; jj < 4; ++jj) {
            int i = t + 512 * jj;
            float old = vcur[i];
            vprev[i] = old;
            vcur[i] = wv[jj] * binv;
        }
        if (t == 0) { alph[st] = alpha; betv[st] = beta; }
        bprev = beta;
        __syncthreads();
    }
    if (t == 0) {
        // Sturm bisection for lam_max of tridiagonal (alph, betv), scaled domain [0,1]
        float lo = 0.0f, hi = 1.00001f;
        for (int bi = 0; bi < 48; ++bi) {
            float mid = 0.5f * (lo + hi);
            int neg = 0;
            float d = alph[0] - mid;
            if (fabsf(d) < 1e-30f) d = -1e-30f;
            neg += (d < 0.0f);
            for (int i = 1; i < LM; ++i) {
                d = (alph[i] - mid) - betv[i - 1] * betv[i - 1] / d;
                if (fabsf(d) < 1e-30f) d = -1e-30f;
                neg += (d < 0.0f);
            }
            if (neg >= LM) hi = mid; else lo = mid;
        }
        lamOut[0] = lamG * 0.5f * (lo + hi) + 1e-8f;
    }
}

// ---------------- bf16 MFMA GEMM, 512 thr, BM=64 BN=256 BK=32, frag-order LDS, dbuf -------
// out[m][n] = sum_k A[m][k] * BT[n][k]
// TA: 1 = A bf16 | 2 = A_eff = (2/lam)*A_bf16 - Aaux_f32
// EPI: 0 = store bf16 | 1 = +bias,LN,relu,+resid -> f32+bf16 | 2 = +bias,+resid,LN -> f32(+bf16) | 3 = +bias,gelu -> bf16
template <int TA, int EPI>
__global__ __launch_bounds__(512) void k_gemm(
    const bf16* __restrict__ A0, const float* __restrict__ Aaux, const bf16* __restrict__ BTg,
    float* __restrict__ outF, bf16* __restrict__ outB,
    const float* __restrict__ bias, const float* __restrict__ resid,
    const float* __restrict__ gam, const float* __restrict__ bet,
    const float* __restrict__ lamPtr,
    int K, long aZ, long btZ, long outZrows, int ldOut)
{
    __shared__ __align__(16) char lds[8192 + 34816];
    bf16* As0 = (bf16*)lds;
    bf16* Bs0 = (bf16*)(lds + 8192);

    int t = threadIdx.x;
    int w = t >> 6, lane = t & 63;
    int q = lane >> 4, l15 = lane & 15;
    int rowBlk = blockIdx.x * 64;
    int colB = blockIdx.y * 256;
    const bf16* A = A0 + (long)blockIdx.z * aZ;
    const bf16* BT = BTg + (long)blockIdx.z * btZ + (long)blockIdx.y * 256 * (long)K;

    float s2 = 0.0f;
    if (TA == 2) s2 = 2.0f / lamPtr[0];

    int ar = t >> 2, ag = t & 3;
    long aBase = (long)(rowBlk + ar) * K + ag * 8;
    int aLds = (ar >> 4) * 512 + (ag * 16 + (ar & 15)) * 8;
    int br = t >> 1, bg = t & 1;
    long bBase = (long)br * K + bg * 16;
    int bLds = (br >> 4) * BS_STRIDE + (br & 15) * 8 + bg * 256;
    int wm = (w & 1) * 2, wn = (w >> 1) * 4;

    f32x4 acc[2][4];
#pragma unroll
    for (int i = 0; i < 2; ++i)
#pragma unroll
        for (int j = 0; j < 4; ++j) acc[i][j] = (f32x4){0.0f, 0.0f, 0.0f, 0.0f};

    uint4 ra; uint4 rb[2];
    auto loadT = [&](int kt) {
        if (t < 256) {
            if (TA == 1) {
                ra = *(const uint4*)(A + aBase + kt);
            } else {
                union { bf16 h[8]; uint4 u; } in; in.u = *(const uint4*)(A + aBase + kt);
                const float* p = Aaux + aBase + kt;
                float4 f0 = *(const float4*)p, f1 = *(const float4*)(p + 4);
                float xa[8] = {f0.x, f0.y, f0.z, f0.w, f1.x, f1.y, f1.z, f1.w};
                union { bf16 h[8]; uint4 u; } pk;
#pragma unroll
                for (int j = 0; j < 8; ++j) pk.h[j] = (bf16)(s2 * (float)in.h[j] - xa[j]);
                ra = pk.u;
            }
        }
        const bf16* pb = BT + bBase + kt;
        rb[0] = *(const uint4*)pb;
        rb[1] = *(const uint4*)(pb + 8);
    };
    int nIter = K >> 5;
    loadT(0);
    for (int it = 0; it < nIter; ++it) {
        bf16* Asp = As0 + (it & 1) * 2048;
        bf16* Bsp = Bs0 + (it & 1) * 8704;
        if (t < 256) *(uint4*)(Asp + aLds) = ra;
        *(uint4*)(Bsp + bLds) = rb[0];
        *(uint4*)(Bsp + bLds + 128) = rb[1];
        __syncthreads();
        if (it + 1 < nIter) loadT((it + 1) * 32);
        bf16x8 af[2], bfr[4];
#pragma unroll
        for (int mf = 0; mf < 2; ++mf) af[mf] = *(const bf16x8*)(Asp + (wm + mf) * 512 + lane * 8);
#pragma unroll
        for (int i = 0; i < 4; ++i) bfr[i] = *(const bf16x8*)(Bsp + (wn + i) * BS_STRIDE + lane * 8);
#pragma unroll
        for (int mf = 0; mf < 2; ++mf)
#pragma unroll
            for (int i = 0; i < 4; ++i)
                acc[mf][i] = __builtin_amdgcn_mfma_f32_16x16x32_bf16(af[mf], bfr[i], acc[mf][i], 0, 0, 0);
    }

    long zBase = (long)blockIdx.z * outZrows;

    if (EPI == 0) {
#pragma unroll
        for (int mf = 0; mf < 2; ++mf)
#pragma unroll
            for (int i = 0; i < 4; ++i) {
                int col = colB + (wn + i) * 16 + l15;
#pragma unroll
                for (int r = 0; r < 4; ++r)
                    outB[(zBase + rowBlk + (wm + mf) * 16 + q * 4 + r) * (long)ldOut + col] = (bf16)acc[mf][i][r];
            }
        return;
    }
    if (EPI == 3) {
#pragma unroll
        for (int mf = 0; mf < 2; ++mf)
#pragma unroll
            for (int i = 0; i < 4; ++i) {
                int col = colB + (wn + i) * 16 + l15;
                float bi = bias[col];
#pragma unroll
                for (int r = 0; r < 4; ++r) {
                    float v = acc[mf][i][r] + bi;
                    float g = 0.5f * v * (1.0f + erff(v * 0.70710678118654752440f));
                    outB[(zBase + rowBlk + (wm + mf) * 16 + q * 4 + r) * (long)ldOut + col] = (bf16)g;
                }
            }
        return;
    }
    // EPI 1/2: layernorm across the 256-col row; rows split (w&1), col-chunks (w>>1)
    float s[2][4], sq[2][4];
#pragma unroll
    for (int mf = 0; mf < 2; ++mf)
#pragma unroll
        for (int r = 0; r < 4; ++r) { s[mf][r] = 0.0f; sq[mf][r] = 0.0f; }
#pragma unroll
    for (int mf = 0; mf < 2; ++mf)
#pragma unroll
        for (int i = 0; i < 4; ++i) {
            int col = colB + (wn + i) * 16 + l15;
            float bi = bias[col];
#pragma unroll
            for (int r = 0; r < 4; ++r) {
                float v = acc[mf][i][r] + bi;
                if (EPI == 2) v += resid[(zBase + rowBlk + (wm + mf) * 16 + q * 4 + r) * 256 + col];
                acc[mf][i][r] = v;
                s[mf][r] += v; sq[mf][r] += v * v;
            }
        }
#pragma unroll
    for (int off = 1; off <= 8; off <<= 1)
#pragma unroll
        for (int mf = 0; mf < 2; ++mf)
#pragma unroll
            for (int r = 0; r < 4; ++r) {
                s[mf][r] += __shfl_xor(s[mf][r], off);
                sq[mf][r] += __shfl_xor(sq[mf][r], off);
            }
    __syncthreads();  // GEMM LDS dead; reuse for LN scratch
    float* sLN = (float*)lds;           // [4 col-chunks][64 rows][2]
    float* mr  = (float*)(lds + 2048);  // [64 rows][2]
    if (l15 == 0) {
#pragma unroll
        for (int mf = 0; mf < 2; ++mf)
#pragma unroll
            for (int r = 0; r < 4; ++r) {
                int row = (wm + mf) * 16 + q * 4 + r;
                sLN[((w >> 1) * 64 + row) * 2 + 0] = s[mf][r];
                sLN[((w >> 1) * 64 + row) * 2 + 1] = sq[mf][r];
            }
    }
    __syncthreads();
    if (t < 64) {
        float ss = 0, sqq = 0;
#pragma unroll
        for (int c4 = 0; c4 < 4; ++c4) {
            ss += sLN[(c4 * 64 + t) * 2 + 0];
            sqq += sLN[(c4 * 64 + t) * 2 + 1];
        }
        float mean = ss * (1.0f / 256.0f);
        float var = sqq * (1.0f / 256.0f) - mean * mean;
        mr[t * 2 + 0] = mean;
        mr[t * 2 + 1] = rsqrtf(var + 1e-5f);
    }
    __syncthreads();
#pragma unroll
    for (int mf = 0; mf < 2; ++mf)
#pragma unroll
        for (int r = 0; r < 4; ++r) {
            int row = (wm + mf) * 16 + q * 4 + r;
            float mean = mr[row * 2 + 0], rs = mr[row * 2 + 1];
            long gRow = zBase + rowBlk + row;
#pragma unroll
            for (int i = 0; i < 4; ++i) {
                int col = colB + (wn + i) * 16 + l15;
                float v = (acc[mf][i][r] - mean) * rs * gam[col] + bet[col];
                if (EPI == 1) v = fmaxf(v, 0.0f) + resid[gRow * 256 + col];
                long oi = gRow * (long)ldOut + col;
                outF[oi] = v;
                if (outB) outB[oi] = (bf16)v;
            }
        }
}

// ---------------- sparse gather attention: block=(b,row), wave=head, lane=dim ----------------
__global__ __launch_bounds__(256) void k_attn(const bf16* __restrict__ qg, const bf16* __restrict__ kg,
                                              const bf16* __restrict__ vg, bf16* __restrict__ og,
                                              const int* __restrict__ cnt, const unsigned short* __restrict__ cols)
{
    __shared__ unsigned short sc[64];
    __shared__ float sp[4][64];
    int row = blockIdx.x;
    int b = row >> 11, i = row & 2047;
    int tid = threadIdx.x, h = tid >> 6, lane = tid & 63;
    int c = cnt[i];
    if (tid < 64) sc[tid] = cols[(long)i * 64 + tid];
    __syncthreads();
    long qoff = (long)row * 256 + h * 64 + lane;
    float qd = (float)qg[qoff];
    long kvBase = (long)b * 2048;
    for (int j = 0; j < c; ++j) {
        int col = sc[j];
        float kd = (float)kg[(kvBase + col) * 256 + h * 64 + lane];
        float p = qd * kd;
#pragma unroll
        for (int off = 32; off >= 1; off >>= 1) p += __shfl_xor(p, off);
        if (lane == 0) sp[h][j] = p * 0.125f;
    }
    __syncthreads();
    float sj = (lane < c) ? sp[h][lane] : -3.0e38f;
    float mx = sj;
#pragma unroll
    for (int off = 32; off >= 1; off >>= 1) mx = fmaxf(mx, __shfl_xor(mx, off));
    float e = (lane < c) ? __expf(sj - mx) : 0.0f;
    float ssum = e;
#pragma unroll
    for (int off = 32; off >= 1; off >>= 1) ssum += __shfl_xor(ssum, off);
    if (lane < c) sp[h][lane] = e / ssum;
    __syncthreads();
    float acc = 0.0f;
    for (int j = 0; j < c; ++j) {
        int col = sc[j];
        acc += sp[h][j] * (float)vg[(kvBase + col) * 256 + h * 64 + lane];
    }
    og[qoff] = (bf16)acc;
}

// ---------------- launcher ----------------
extern "C" void kernel_launch(void* const* d_in, const int* in_sizes, int n_in,
                              void* d_out, int out_size, void* d_ws, size_t ws_size,
                              hipStream_t stream)
{
    const float* x   = (const float*)d_in[0];
    const float* L   = (const float*)d_in[1];
    const float* adj = (const float*)d_in[2];
    const float* Wc  = (const float*)d_in[3];
    const float* bc  = (const float*)d_in[4];
    const float* g1  = (const float*)d_in[5];
    const float* be1 = (const float*)d_in[6];
    const float* Wq  = (const float*)d_in[7];
    const float* Wk  = (const float*)d_in[8];
    const float* Wv  = (const float*)d_in[9];
    const float* Wo  = (const float*)d_in[10];
    const float* bo  = (const float*)d_in[11];
    const float* g2  = (const float*)d_in[12];
    const float* be2 = (const float*)d_in[13];
    const float* W1  = (const float*)d_in[14];
    const float* b1  = (const float*)d_in[15];
    const float* W2  = (const float*)d_in[16];
    const float* b2  = (const float*)d_in[17];
    const float* g3  = (const float*)d_in[18];
    const float* be3 = (const float*)d_in[19];
    float* out = (float*)d_out;

    char* ws = (char*)d_ws;
    size_t off = 0;
    auto alloc = [&](size_t bytes) -> void* {
        void* p = ws + off;
        off = (off + bytes + 255) & ~(size_t)255;
        return p;
    };
    float* lam           = (float*)alloc(256);
    int* cnt             = (int*)alloc(2048 * 4);
    unsigned short* cols = (unsigned short*)alloc(2048 * 64 * 2);
    bf16* WcT = (bf16*)alloc(65536 * 2);
    bf16* WqT = (bf16*)alloc(65536 * 2);   // WqT,WkT,WvT contiguous (btZ = 65536)
    bf16* WkT = (bf16*)alloc(65536 * 2);
    bf16* WvT = (bf16*)alloc(65536 * 2);
    bf16* WoT = (bf16*)alloc(65536 * 2);
    bf16* W1T = (bf16*)alloc(131072 * 2);
    bf16* W2T = (bf16*)alloc(131072 * 2);
    bf16* xT  = (bf16*)alloc((size_t)4 * 256 * 2048 * 2);
    bf16* xp0 = (bf16*)alloc((size_t)8192 * 256 * 2);
    float* x1f = (float*)alloc((size_t)8192 * 256 * 4);
    bf16* x1b  = (bf16*)alloc((size_t)8192 * 256 * 2);
    bf16* qb   = (bf16*)alloc((size_t)3 * 8192 * 256 * 2);
    bf16* ob   = (bf16*)alloc((size_t)8192 * 256 * 2);
    float* x2f = (float*)alloc((size_t)8192 * 256 * 4);
    bf16* x2b  = (bf16*)alloc((size_t)8192 * 256 * 2);
    bf16* m1   = (bf16*)alloc((size_t)8192 * 512 * 2);
    (void)in_sizes; (void)n_in; (void)out_size; (void)ws_size;

    dim3 blk(256), blkG(512);
    // transposes + CSR, one launch
    k_pre<<<dim3(16, 64, 12), blk, 0, stream>>>(Wc, Wq, Wk, Wv, Wo, W1, W2, x, adj,
                                                WcT, WqT, WkT, WvT, WoT, W1T, W2T, xT, cnt, cols);
    // block 0: Lanczos -> lam ; blocks 1..128: xp0[b] = L @ x[b]
    k_main<<<dim3(129), blkG, 0, stream>>>(cnt, cols, lam, L, xT, xp0);
    // x1 = relu(LN((s2*xp0 - x)@Wc + bc; g1,be1)) + x
    k_gemm<2, 1><<<dim3(128, 1, 1), blkG, 0, stream>>>(
        xp0, x, WcT, x1f, x1b, bc, x, g1, be1, lam,
        256, 0L, 0L, 0L, 256);
    // q,k,v = x1 @ {Wq,Wk,Wv}
    k_gemm<1, 0><<<dim3(128, 1, 3), blkG, 0, stream>>>(
        x1b, nullptr, WqT, nullptr, qb, nullptr, nullptr, nullptr, nullptr, nullptr,
        256, 0L, 65536L, 8192L, 256);
    // sparse masked attention
    bf16* kb  = qb + (size_t)8192 * 256;
    bf16* vb2 = qb + (size_t)2 * 8192 * 256;
    k_attn<<<dim3(8192), blk, 0, stream>>>(qb, kb, vb2, ob, cnt, cols);
    // x2 = LN(x1 + o@Wo + bo; g2,be2)
    k_gemm<1, 2><<<dim3(128, 1, 1), blkG, 0, stream>>>(
        ob, nullptr, WoT, x2f, x2b, bo, x1f, g2, be2, nullptr,
        256, 0L, 0L, 0L, 256);
    // m1 = gelu(x2@W1 + b1)
    k_gemm<1, 3><<<dim3(128, 2, 1), blkG, 0, stream>>>(
        x2b, nullptr, W1T, nullptr, m1, b1, nullptr, nullptr, nullptr, nullptr,
        256, 0L, 0L, 0L, 512);
    // out = LN(x2 + m1@W2 + b2; g3,be3)
    k_gemm<1, 2><<<dim3(128, 1, 1), blkG, 0, stream>>>(
        m1, nullptr, W2T, out, nullptr, b2, x2f, g3, be3, nullptr,
        512, 0L, 0L, 0L, 256);
}